// Round 10
// baseline (121.059 us; speedup 1.0000x reference)
//
#include <hip/hip_runtime.h>
#include <hip/hip_bf16.h>

// Problem constants
static constexpr int Bn = 8, Cn = 128, Hn = 64, Wn = 64, Con = 128;
static constexpr int KKn = 9, DGn = 2, Cgn = 64;
static constexpr int HOn = 64, WOn = 64;
static constexpr int PITCH = 72;     // bf16 row pitch for s_val
static constexpr int OMP = 34;       // s_om row pitch (shorts)

typedef short short8 __attribute__((ext_vector_type(8)));
typedef float f32x4  __attribute__((ext_vector_type(4)));

__device__ __forceinline__ unsigned short f2bf(float f) {
    unsigned u = __float_as_uint(f);
    u += 0x7fff + ((u >> 16) & 1);          // round-to-nearest-even
    return (unsigned short)(u >> 16);
}
__device__ __forceinline__ float bf2f(unsigned short h) {
    return __uint_as_float(((unsigned)h) << 16);
}

// ---------------------------------------------------------------------------
// Kernel P: merged prep.
// Blocks [0,512):    x NCHW fp32 -> x_t NHWC bf16 (float4 loads, LDS transpose).
// Blocks [512,1088): main weight -> MFMA B-frag order wt2[gk][ks][tile][lane][8].
// Blocks [1088,1232): offset weight -> owf[g][ks=tap*2+ch][nt][lane][8].
// ---------------------------------------------------------------------------
__global__ __launch_bounds__(256) void prep(const float* __restrict__ x,
                                            const float* __restrict__ w,
                                            const float* __restrict__ ow,
                                            unsigned short* __restrict__ xt,
                                            unsigned short* __restrict__ wt2,
                                            unsigned short* __restrict__ owf) {
    __shared__ unsigned short s[128 * 64];       // 16 KB [c][x]
    const int blk = blockIdx.x;
    const int t = threadIdx.x;
    if (blk < 512) {
        const int b = blk & 7, y = blk >> 3;
        const float* src = x + ((size_t)b * Cn * Hn + y) * Wn;
#pragma unroll
        for (int i = 0; i < 8; ++i) {
            int e = t + i * 256;                 // float4 id [0,2048)
            int c = e >> 4, x4 = e & 15;
            float4 v = *(const float4*)&src[(size_t)c * (Hn * Wn) + x4 * 4];
            s[c * 64 + x4 * 4 + 0] = f2bf(v.x);
            s[c * 64 + x4 * 4 + 1] = f2bf(v.y);
            s[c * 64 + x4 * 4 + 2] = f2bf(v.z);
            s[c * 64 + x4 * 4 + 3] = f2bf(v.w);
        }
        __syncthreads();
        unsigned short* dst = xt + ((size_t)(b * 64 + y) * 64) * 128;
#pragma unroll
        for (int i = 0; i < 4; ++i) {
            int e = t + i * 256;                 // short8 id [0,1024)
            int xc = e >> 4;
            int c0 = (e & 15) * 8;
            short8 v;
#pragma unroll
            for (int j = 0; j < 8; ++j) v[j] = (short)s[(c0 + j) * 64 + xc];
            *(short8*)&dst[(size_t)e * 8] = v;
        }
    } else if (blk < 1088) {
        int e    = (blk - 512) * 256 + t;        // [0,147456)
        int j    = e & 7;
        int lane = (e >> 3) & 63;
        int tile = (e >> 9) & 7;
        int ks   = (e >> 12) & 1;
        int gk   = e >> 13;                      // 0..17
        int g = gk / 9, k = gk - g * 9;
        int oc = tile * 16 + (lane & 15);
        int c  = ks * 32 + (lane >> 4) * 8 + j;
        wt2[e] = f2bf(w[((size_t)oc * Cn + g * Cgn + c) * KKn + k]);
    } else {
        int e = (blk - 1088) * 256 + t;          // [0,36864)
        int g  = e / 18432;
        int r  = e - g * 18432;
        int ks = r >> 10;
        int r2 = r & 1023;
        int nt = r2 >> 9;
        int lane = (r2 >> 3) & 63;
        int j  = r2 & 7;
        int tap = ks >> 1, chalf = ks & 1;
        int oc_l = nt * 16 + (lane & 15);
        int c = chalf * 32 + (lane >> 4) * 8 + j;
        float v = 0.f;
        if (oc_l < 27)
            v = ow[((size_t)(g * 27 + oc_l) * Cgn + c) * KKn + tap];
        owf[e] = f2bf(v);
    }
}

// ---------------------------------------------------------------------------
// Kernel 2: FULLY FUSED offset-conv + deformable gather + bf16 MFMA.
// Grid 1024 = (b = id&7 XCD swizzle, ho, mh), 4 blk/CU.
// P0: om row via MFMA GEMM into s_om (R9-proven, bit-identical to R7 order).
// P1: sampling params from s_om.
// P2: 18-gk loop, PING-PONG s_val double buffer, ONE barrier per gk:
//     produce(k) writes buf[k&1]; barrier; MFMA reads buf[k&1]; produce(k+1)
//     writes buf[(k+1)&1] with no trailing barrier (its prior readers were
//     separated by barrier k). Gather loads of k+1 overlap MFMA of k.
// LDS: 2*4608 (s_val) + 9216 (s_cw) + 2304 (s_pk) + 3672 (s_om) = 24408 B.
// ---------------------------------------------------------------------------
__global__ __launch_bounds__(256, 4) void dcn_fused(const unsigned short* __restrict__ xt,
                                                    const unsigned short* __restrict__ owf,
                                                    const float* __restrict__ ob,
                                                    const unsigned short* __restrict__ wt2,
                                                    float* __restrict__ out) {
    __shared__ __align__(16) unsigned short s_val[2][32 * PITCH];   // [buf][pos][c]
    __shared__ float4 s_cw[18][32];
    __shared__ int    s_pk[18][32];
    __shared__ unsigned short s_om[54 * OMP];                       // [c54][pos]

    const int t  = threadIdx.x;
    const int id = blockIdx.x;               // [0, 1024)
    const int b  = id & 7;                   // XCD-aware swizzle
    const int ho = (id >> 3) & 63;
    const int mh = id >> 9;                  // pos half 0/1

    const int lane = t & 63;
    const int wv   = t >> 6;                 // wave id 0..3
    const int lr   = lane & 15;              // MFMA row/col part
    const int lk   = (lane >> 4) * 8;        // MFMA k offset (shorts)
    const int q    = lane >> 4;              // D row quad

    const unsigned short* xb0 = xt + (size_t)b * (Hn * Wn * Cn);
    const short8 zz = {0, 0, 0, 0, 0, 0, 0, 0};

    // ---- P0: offset-conv GEMM for this half-row (bit-identical to R7) ----
    {
        const int cg = wv >> 1;              // conv/deform group
        const int nh = wv & 1;               // n-tile (oc 16-block)
        const int oc_l = nh * 16 + lr;
        float bias = (oc_l < 27) ? ob[cg * 27 + oc_l] : 0.f;
        f32x4 oacc[2];
        oacc[0] = (f32x4){bias, bias, bias, bias};
        oacc[1] = (f32x4){bias, bias, bias, bias};

        const unsigned short* xb = xb0 + cg * Cgn;
        const unsigned short* wf = owf + (size_t)cg * 18432;

        for (int tap = 0; tap < 9; ++tap) {
            int ky = tap / 3, kx = tap - ky * 3;
            int y = ho - 2 + 2 * ky;
            if (y < 0 || y >= Hn) continue;  // wave-uniform skip (zero pad)
#pragma unroll
            for (int ch = 0; ch < 2; ++ch) {
                int kssl = tap * 2 + ch;
                short8 bv = *(const short8*)&wf[(size_t)kssl * 1024 + nh * 512 + lane * 8];
#pragma unroll
                for (int mt = 0; mt < 2; ++mt) {
                    int wo = mh * 32 + mt * 16 + lr;
                    int xc = wo - 2 + 2 * kx;
                    bool vx = (xc >= 0) & (xc < Wn);
                    int xcc = min(max(xc, 0), Wn - 1);
                    short8 av = *(const short8*)&xb[((size_t)y * Wn + xcc) * Cn + ch * 32 + lk];
                    av = vx ? av : zz;
                    oacc[mt] = __builtin_amdgcn_mfma_f32_16x16x32_bf16(av, bv, oacc[mt], 0, 0, 0);
                }
            }
        }
        if (oc_l < 27) {
            int c54 = cg * 27 + oc_l;
#pragma unroll
            for (int mt = 0; mt < 2; ++mt)
#pragma unroll
                for (int r = 0; r < 4; ++r)
                    s_om[c54 * OMP + mt * 16 + q * 4 + r] = f2bf(oacc[mt][r]);
        }
    }
    __syncthreads();

    // ---- P1: sampling params for all (gk, pos) of this half-row ----
    for (int e = t; e < 18 * 32; e += 256) {
        int pos = e & 31;
        int wo  = mh * 32 + pos;
        int gk  = e >> 5;
        int g  = gk / 9, k = gk - g * 9;
        int ky = k / 3,  kx = k - ky * 3;
        float offy = bf2f(s_om[(g * 18 + k * 2 + 0) * OMP + pos]);
        float offx = bf2f(s_om[(g * 18 + k * 2 + 1) * OMP + pos]);
        float mk   = bf2f(s_om[(36 + g * 9 + k) * OMP + pos]);
        mk = 2.0f / (1.0f + __expf(-mk));

        float py = offy + (float)(ky * 2 + ho - 2);
        float px = offx + (float)(kx * 2 + wo - 2);
        float fy = floorf(py), fx = floorf(px);
        int   y0 = (int)fy,    x0 = (int)fx;
        float wy = py - fy,    wx = px - fx;

        bool vy0 = (y0 >= 0) & (y0 < Hn);
        bool vy1 = (y0 + 1 >= 0) & (y0 + 1 < Hn);
        bool vx0 = (x0 >= 0) & (x0 < Wn);
        bool vx1 = (x0 + 1 >= 0) & (x0 + 1 < Wn);
        float4 cw;
        cw.x = (vy0 & vx0) ? (1.f - wy) * (1.f - wx) * mk : 0.f;
        cw.y = (vy0 & vx1) ? (1.f - wy) * wx * mk : 0.f;
        cw.z = (vy1 & vx0) ? wy * (1.f - wx) * mk : 0.f;
        cw.w = (vy1 & vx1) ? wy * wx * mk : 0.f;

        int y0c = min(max(y0, 0), Hn - 1);
        int y1c = min(max(y0 + 1, 0), Hn - 1);
        int x0c = min(max(x0, 0), Wn - 1);
        int x1c = min(max(x0 + 1, 0), Wn - 1);
        s_cw[gk][pos] = cw;
        s_pk[gk][pos] = y0c | (y1c << 8) | (x0c << 16) | (x1c << 24);
    }
    __syncthreads();

    // ---- P2: gather + MFMA loop, ping-pong buffer, 1 barrier/gk ----
    const int pos = t >> 3;                  // gather: position 0..31
    const int cq  = (t & 7) * 8;             // gather: 8-ch chunk (group-local)

    f32x4 acc[2][2];
#pragma unroll
    for (int mt = 0; mt < 2; ++mt)
#pragma unroll
        for (int nt = 0; nt < 2; ++nt) acc[mt][nt] = (f32x4){0.f, 0.f, 0.f, 0.f};

    for (int gk = 0; gk < 18; ++gk) {
        unsigned short* sv = s_val[gk & 1];

        // ---- B fragments, lane-contiguous from wt2 (L2-hot) ----
        const unsigned short* wf = wt2 + (size_t)gk * 8192;
        short8 bfr[2][2];
#pragma unroll
        for (int ks = 0; ks < 2; ++ks)
#pragma unroll
            for (int nt = 0; nt < 2; ++nt)
                bfr[ks][nt] = *(const short8*)&wf[(size_t)(ks * 8 + wv * 2 + nt) * 512 + lane * 8];

        // ---- gather: 4 corners x 8 channels, coalesced NHWC loads ----
        {
            const int g = gk / 9;
            float4 cw = s_cw[gk][pos];
            int pk  = s_pk[gk][pos];
            int y0c = pk & 255, y1c = (pk >> 8) & 255;
            int x0c = (pk >> 16) & 255, x1c = (pk >> 24) & 255;
            const unsigned short* xb = xb0 + g * Cgn + cq;
            short8 a00 = *(const short8*)&xb[((size_t)y0c * Wn + x0c) * Cn];
            short8 a01 = *(const short8*)&xb[((size_t)y0c * Wn + x1c) * Cn];
            short8 a10 = *(const short8*)&xb[((size_t)y1c * Wn + x0c) * Cn];
            short8 a11 = *(const short8*)&xb[((size_t)y1c * Wn + x1c) * Cn];
            short8 h0;
#pragma unroll
            for (int i = 0; i < 8; ++i) {
                float v = cw.x * bf2f((unsigned short)a00[i]) +
                          cw.y * bf2f((unsigned short)a01[i]) +
                          cw.z * bf2f((unsigned short)a10[i]) +
                          cw.w * bf2f((unsigned short)a11[i]);
                h0[i] = (short)f2bf(v);
            }
            *(short8*)&sv[pos * PITCH + cq] = h0;
        }
        __syncthreads();

        // ---- 2 K-steps of MFMA (no trailing barrier: next write goes to
        //      the other buffer, separated from this buffer's readers) ----
#pragma unroll
        for (int ks = 0; ks < 2; ++ks) {
            short8 af[2];
#pragma unroll
            for (int mt = 0; mt < 2; ++mt)
                af[mt] = *(const short8*)&sv[(mt * 16 + lr) * PITCH + ks * 32 + lk];
#pragma unroll
            for (int mt = 0; mt < 2; ++mt)
#pragma unroll
                for (int nt = 0; nt < 2; ++nt)
                    acc[mt][nt] = __builtin_amdgcn_mfma_f32_16x16x32_bf16(
                        af[mt], bfr[ks][nt], acc[mt][nt], 0, 0, 0);
        }
    }

    // ---- epilogue: D col = oc, row = pos (within this 32-pos half) ----
#pragma unroll
    for (int mt = 0; mt < 2; ++mt)
#pragma unroll
        for (int nt = 0; nt < 2; ++nt) {
            int oc = wv * 32 + nt * 16 + lr;
            int p0 = mh * 32 + mt * 16 + q * 4;
            float4 v = {acc[mt][nt][0], acc[mt][nt][1], acc[mt][nt][2], acc[mt][nt][3]};
            *(float4*)&out[(((size_t)b * Con + oc) * HOn + ho) * WOn + p0] = v;
        }
}

// ---------------------------------------------------------------------------
extern "C" void kernel_launch(void* const* d_in, const int* in_sizes, int n_in,
                              void* d_out, int out_size, void* d_ws, size_t ws_size,
                              hipStream_t stream) {
    const float* x  = (const float*)d_in[0];   // [8,128,64,64]
    const float* ow = (const float*)d_in[1];   // [54,64,3,3]
    const float* ob = (const float*)d_in[2];   // [54]
    const float* w  = (const float*)d_in[3];   // [128,128,3,3]
    float* out = (float*)d_out;                // [8,128,64,64]

    // ws: x_t bf16 8,388,608 | wt2 294,912 | owf 73,728
    unsigned short* xt  = (unsigned short*)d_ws;
    unsigned short* wt2 = (unsigned short*)((char*)d_ws + 8388608);
    unsigned short* owf = (unsigned short*)((char*)d_ws + 8388608 + 294912);

    hipLaunchKernelGGL(prep, dim3(1232), dim3(256), 0, stream,
                       x, w, ow, xt, wt2, owf);
    hipLaunchKernelGGL(dcn_fused, dim3(1024), dim3(256), 0, stream,
                       xt, owf, ob, wt2, out);
}

// Round 11
// 120.155 us; speedup vs baseline: 1.0075x; 1.0075x over previous
//
#include <hip/hip_runtime.h>
#include <hip/hip_bf16.h>

// Problem constants
static constexpr int Bn = 8, Cn = 128, Hn = 64, Wn = 64, Con = 128;
static constexpr int KKn = 9, DGn = 2, Cgn = 64;
static constexpr int HOn = 64, WOn = 64;
static constexpr int PITCH = 72;     // bf16 row pitch for s_val
static constexpr int OMP = 34;       // s_om row pitch (shorts)

typedef short short8 __attribute__((ext_vector_type(8)));
typedef float f32x4  __attribute__((ext_vector_type(4)));

__device__ __forceinline__ unsigned short f2bf(float f) {
    unsigned u = __float_as_uint(f);
    u += 0x7fff + ((u >> 16) & 1);          // round-to-nearest-even
    return (unsigned short)(u >> 16);
}
__device__ __forceinline__ float bf2f(unsigned short h) {
    return __uint_as_float(((unsigned)h) << 16);
}

// ---------------------------------------------------------------------------
// Kernel P: merged prep (R10-proven).
// Blocks [0,512):    x NCHW fp32 -> x_t NHWC bf16 (float4 loads, LDS transpose).
// Blocks [512,1088): main weight -> MFMA B-frag order wt2[gk][ks][tile][lane][8].
// Blocks [1088,1232): offset weight -> owf[g][ks=tap*2+ch][nt][lane][8].
// ---------------------------------------------------------------------------
__global__ __launch_bounds__(256) void prep(const float* __restrict__ x,
                                            const float* __restrict__ w,
                                            const float* __restrict__ ow,
                                            unsigned short* __restrict__ xt,
                                            unsigned short* __restrict__ wt2,
                                            unsigned short* __restrict__ owf) {
    __shared__ unsigned short s[128 * 64];       // 16 KB [c][x]
    const int blk = blockIdx.x;
    const int t = threadIdx.x;
    if (blk < 512) {
        const int b = blk & 7, y = blk >> 3;
        const float* src = x + ((size_t)b * Cn * Hn + y) * Wn;
#pragma unroll
        for (int i = 0; i < 8; ++i) {
            int e = t + i * 256;                 // float4 id [0,2048)
            int c = e >> 4, x4 = e & 15;
            float4 v = *(const float4*)&src[(size_t)c * (Hn * Wn) + x4 * 4];
            s[c * 64 + x4 * 4 + 0] = f2bf(v.x);
            s[c * 64 + x4 * 4 + 1] = f2bf(v.y);
            s[c * 64 + x4 * 4 + 2] = f2bf(v.z);
            s[c * 64 + x4 * 4 + 3] = f2bf(v.w);
        }
        __syncthreads();
        unsigned short* dst = xt + ((size_t)(b * 64 + y) * 64) * 128;
#pragma unroll
        for (int i = 0; i < 4; ++i) {
            int e = t + i * 256;                 // short8 id [0,1024)
            int xc = e >> 4;
            int c0 = (e & 15) * 8;
            short8 v;
#pragma unroll
            for (int j = 0; j < 8; ++j) v[j] = (short)s[(c0 + j) * 64 + xc];
            *(short8*)&dst[(size_t)e * 8] = v;
        }
    } else if (blk < 1088) {
        int e    = (blk - 512) * 256 + t;        // [0,147456)
        int j    = e & 7;
        int lane = (e >> 3) & 63;
        int tile = (e >> 9) & 7;
        int ks   = (e >> 12) & 1;
        int gk   = e >> 13;                      // 0..17
        int g = gk / 9, k = gk - g * 9;
        int oc = tile * 16 + (lane & 15);
        int c  = ks * 32 + (lane >> 4) * 8 + j;
        wt2[e] = f2bf(w[((size_t)oc * Cn + g * Cgn + c) * KKn + k]);
    } else {
        int e = (blk - 1088) * 256 + t;          // [0,36864)
        int g  = e / 18432;
        int r  = e - g * 18432;
        int ks = r >> 10;
        int r2 = r & 1023;
        int nt = r2 >> 9;
        int lane = (r2 >> 3) & 63;
        int j  = r2 & 7;
        int tap = ks >> 1, chalf = ks & 1;
        int oc_l = nt * 16 + (lane & 15);
        int c = chalf * 32 + (lane >> 4) * 8 + j;
        float v = 0.f;
        if (oc_l < 27)
            v = ow[((size_t)(g * 27 + oc_l) * Cgn + c) * KKn + tap];
        owf[e] = f2bf(v);
    }
}

// ---- pipelined-P2 helpers -------------------------------------------------
struct GS { float4 cw; short8 a00, a01, a10, a11; };

__device__ __forceinline__ void bpref(const unsigned short* __restrict__ wt2,
                                      int gk, int wv, int lane, short8 (&bfr)[2][2]) {
    const unsigned short* wf = wt2 + (size_t)gk * 8192;
#pragma unroll
    for (int ks = 0; ks < 2; ++ks)
#pragma unroll
        for (int nt = 0; nt < 2; ++nt)
            bfr[ks][nt] = *(const short8*)&wf[(size_t)(ks * 8 + wv * 2 + nt) * 512 + lane * 8];
}

__device__ __forceinline__ void gpref(const unsigned short* __restrict__ xb0q,
                                      const float4 (*s_cw)[32], const int (*s_pk)[32],
                                      int gk, int pos, GS& g) {
    g.cw = s_cw[gk][pos];
    int pk = s_pk[gk][pos];
    int y0c = pk & 255, y1c = (pk >> 8) & 255;
    int x0c = (pk >> 16) & 255, x1c = (pk >> 24) & 255;
    const unsigned short* xb = xb0q + (gk >= 9 ? Cgn : 0);
    g.a00 = *(const short8*)&xb[((size_t)y0c * Wn + x0c) * Cn];
    g.a01 = *(const short8*)&xb[((size_t)y0c * Wn + x1c) * Cn];
    g.a10 = *(const short8*)&xb[((size_t)y1c * Wn + x0c) * Cn];
    g.a11 = *(const short8*)&xb[((size_t)y1c * Wn + x1c) * Cn];
}

__device__ __forceinline__ void gcommit(const GS& g, unsigned short* sv, int pos, int cq) {
    short8 h0;
#pragma unroll
    for (int i = 0; i < 8; ++i) {
        float v = g.cw.x * bf2f((unsigned short)g.a00[i]) +
                  g.cw.y * bf2f((unsigned short)g.a01[i]) +
                  g.cw.z * bf2f((unsigned short)g.a10[i]) +
                  g.cw.w * bf2f((unsigned short)g.a11[i]);
        h0[i] = (short)f2bf(v);
    }
    *(short8*)&sv[pos * PITCH + cq] = h0;
}

__device__ __forceinline__ void mstep(const unsigned short* sv, const short8 (&bfr)[2][2],
                                      int lr, int lk, f32x4 (&acc)[2][2]) {
#pragma unroll
    for (int ks = 0; ks < 2; ++ks) {
        short8 af[2];
#pragma unroll
        for (int mt = 0; mt < 2; ++mt)
            af[mt] = *(const short8*)&sv[(mt * 16 + lr) * PITCH + ks * 32 + lk];
#pragma unroll
        for (int mt = 0; mt < 2; ++mt)
#pragma unroll
            for (int nt = 0; nt < 2; ++nt)
                acc[mt][nt] = __builtin_amdgcn_mfma_f32_16x16x32_bf16(
                    af[mt], bfr[ks][nt], acc[mt][nt], 0, 0, 0);
    }
}

// ---------------------------------------------------------------------------
// Kernel 2: FULLY FUSED offset-conv + deformable gather + bf16 MFMA,
// explicit register-prefetch pipeline.
// Grid 1024 = (b = id&7 XCD swizzle, ho, mh), 4 blk/CU.
// P0: om row via MFMA GEMM into s_om — uniform 9-tap loop, invalid taps
//     contribute exact +0 (A=0) -> bit-identical to R7 order.
// P1: sampling params from s_om (unchanged).
// P2: parity-unrolled pipeline: iter k ISSUES k+1's B-frag + gather loads,
//     THEN runs MFMA(k) from buf[k&1], THEN converts/writes k+1 to the other
//     buffer, then one barrier. Loads hide under the MFMA phase.
//     Race-free: reads of buf[p] in iter k-1 precede barrier(k-1), writes of
//     buf[p] in iter k+1 follow it.
// LDS: 2*4608 (s_val) + 9216 (s_cw) + 2304 (s_pk) + 3672 (s_om) = 24408 B.
// ---------------------------------------------------------------------------
__global__ __launch_bounds__(256, 4) void dcn_fused(const unsigned short* __restrict__ xt,
                                                    const unsigned short* __restrict__ owf,
                                                    const float* __restrict__ ob,
                                                    const unsigned short* __restrict__ wt2,
                                                    float* __restrict__ out) {
    __shared__ __align__(16) unsigned short s_val[2][32 * PITCH];   // [buf][pos][c]
    __shared__ float4 s_cw[18][32];
    __shared__ int    s_pk[18][32];
    __shared__ unsigned short s_om[54 * OMP];                       // [c54][pos]

    const int t  = threadIdx.x;
    const int id = blockIdx.x;               // [0, 1024)
    const int b  = id & 7;                   // XCD-aware swizzle
    const int ho = (id >> 3) & 63;
    const int mh = id >> 9;                  // pos half 0/1

    const int lane = t & 63;
    const int wv   = t >> 6;                 // wave id 0..3
    const int lr   = lane & 15;              // MFMA row/col part
    const int lk   = (lane >> 4) * 8;        // MFMA k offset (shorts)
    const int q    = lane >> 4;              // D row quad

    const unsigned short* xb0 = xt + (size_t)b * (Hn * Wn * Cn);
    const short8 zz = {0, 0, 0, 0, 0, 0, 0, 0};

    // ---- P0: offset-conv GEMM, uniform taps (bit-identical: A=0 adds +0) ----
    {
        const int cg = wv >> 1;              // conv/deform group
        const int nh = wv & 1;               // n-tile (oc 16-block)
        const int oc_l = nh * 16 + lr;
        float bias = (oc_l < 27) ? ob[cg * 27 + oc_l] : 0.f;
        f32x4 oacc[2];
        oacc[0] = (f32x4){bias, bias, bias, bias};
        oacc[1] = (f32x4){bias, bias, bias, bias};

        const unsigned short* xb = xb0 + cg * Cgn;
        const unsigned short* wf = owf + (size_t)cg * 18432;

#pragma unroll
        for (int tap = 0; tap < 9; ++tap) {
            const int ky = tap / 3, kx = tap - ky * 3;
            int y = ho - 2 + 2 * ky;
            bool vy = (y >= 0) & (y < Hn);
            int yc = min(max(y, 0), Hn - 1);
#pragma unroll
            for (int ch = 0; ch < 2; ++ch) {
                short8 bv = *(const short8*)&wf[(size_t)(tap * 2 + ch) * 1024 + nh * 512 + lane * 8];
#pragma unroll
                for (int mt = 0; mt < 2; ++mt) {
                    int wo = mh * 32 + mt * 16 + lr;
                    int xc = wo - 2 + 2 * kx;
                    bool v = vy & (xc >= 0) & (xc < Wn);
                    int xcc = min(max(xc, 0), Wn - 1);
                    short8 av = *(const short8*)&xb[((size_t)yc * Wn + xcc) * Cn + ch * 32 + lk];
                    av = v ? av : zz;
                    oacc[mt] = __builtin_amdgcn_mfma_f32_16x16x32_bf16(av, bv, oacc[mt], 0, 0, 0);
                }
            }
        }
        if (oc_l < 27) {
            int c54 = cg * 27 + oc_l;
#pragma unroll
            for (int mt = 0; mt < 2; ++mt)
#pragma unroll
                for (int r = 0; r < 4; ++r)
                    s_om[c54 * OMP + mt * 16 + q * 4 + r] = f2bf(oacc[mt][r]);
        }
    }
    __syncthreads();

    // ---- P1: sampling params for all (gk, pos) of this half-row ----
    for (int e = t; e < 18 * 32; e += 256) {
        int pos = e & 31;
        int wo  = mh * 32 + pos;
        int gk  = e >> 5;
        int g  = gk / 9, k = gk - g * 9;
        int ky = k / 3,  kx = k - ky * 3;
        float offy = bf2f(s_om[(g * 18 + k * 2 + 0) * OMP + pos]);
        float offx = bf2f(s_om[(g * 18 + k * 2 + 1) * OMP + pos]);
        float mk   = bf2f(s_om[(36 + g * 9 + k) * OMP + pos]);
        mk = 2.0f / (1.0f + __expf(-mk));

        float py = offy + (float)(ky * 2 + ho - 2);
        float px = offx + (float)(kx * 2 + wo - 2);
        float fy = floorf(py), fx = floorf(px);
        int   y0 = (int)fy,    x0 = (int)fx;
        float wy = py - fy,    wx = px - fx;

        bool vy0 = (y0 >= 0) & (y0 < Hn);
        bool vy1 = (y0 + 1 >= 0) & (y0 + 1 < Hn);
        bool vx0 = (x0 >= 0) & (x0 < Wn);
        bool vx1 = (x0 + 1 >= 0) & (x0 + 1 < Wn);
        float4 cw;
        cw.x = (vy0 & vx0) ? (1.f - wy) * (1.f - wx) * mk : 0.f;
        cw.y = (vy0 & vx1) ? (1.f - wy) * wx * mk : 0.f;
        cw.z = (vy1 & vx0) ? wy * (1.f - wx) * mk : 0.f;
        cw.w = (vy1 & vx1) ? wy * wx * mk : 0.f;

        int y0c = min(max(y0, 0), Hn - 1);
        int y1c = min(max(y0 + 1, 0), Hn - 1);
        int x0c = min(max(x0, 0), Wn - 1);
        int x1c = min(max(x0 + 1, 0), Wn - 1);
        s_cw[gk][pos] = cw;
        s_pk[gk][pos] = y0c | (y1c << 8) | (x0c << 16) | (x1c << 24);
    }
    __syncthreads();

    // ---- P2: explicit register-prefetch pipeline, 1 barrier/gk ----
    const int pos = t >> 3;                  // gather: position 0..31
    const int cq  = (t & 7) * 8;             // gather: 8-ch chunk (group-local)
    const unsigned short* xb0q = xb0 + cq;

    f32x4 acc[2][2];
#pragma unroll
    for (int mt = 0; mt < 2; ++mt)
#pragma unroll
        for (int nt = 0; nt < 2; ++nt) acc[mt][nt] = (f32x4){0.f, 0.f, 0.f, 0.f};

    GS gs;
    short8 bfrA[2][2], bfrB[2][2];

    // prologue: stage gk=0 into buf0, prefetch its B-frags
    bpref(wt2, 0, wv, lane, bfrA);
    gpref(xb0q, s_cw, s_pk, 0, pos, gs);
    gcommit(gs, s_val[0], pos, cq);
    __syncthreads();

    for (int g2 = 0; g2 < 9; ++g2) {
        const int k0 = 2 * g2;
        // iter k0 (reads buf0/bfrA): prefetch k0+1, mfma, commit k0+1 -> buf1
        bpref(wt2, k0 + 1, wv, lane, bfrB);
        gpref(xb0q, s_cw, s_pk, k0 + 1, pos, gs);
        mstep(s_val[0], bfrA, lr, lk, acc);
        gcommit(gs, s_val[1], pos, cq);
        __syncthreads();
        // iter k0+1 (reads buf1/bfrB): prefetch k0+2, mfma, commit -> buf0
        if (g2 < 8) {
            bpref(wt2, k0 + 2, wv, lane, bfrA);
            gpref(xb0q, s_cw, s_pk, k0 + 2, pos, gs);
        }
        mstep(s_val[1], bfrB, lr, lk, acc);
        if (g2 < 8) {
            gcommit(gs, s_val[0], pos, cq);
            __syncthreads();
        }
    }

    // ---- epilogue: D col = oc, row = pos (within this 32-pos half) ----
#pragma unroll
    for (int mt = 0; mt < 2; ++mt)
#pragma unroll
        for (int nt = 0; nt < 2; ++nt) {
            int oc = wv * 32 + nt * 16 + lr;
            int p0 = mh * 32 + mt * 16 + q * 4;
            float4 v = {acc[mt][nt][0], acc[mt][nt][1], acc[mt][nt][2], acc[mt][nt][3]};
            *(float4*)&out[(((size_t)b * Con + oc) * HOn + ho) * WOn + p0] = v;
        }
}

// ---------------------------------------------------------------------------
extern "C" void kernel_launch(void* const* d_in, const int* in_sizes, int n_in,
                              void* d_out, int out_size, void* d_ws, size_t ws_size,
                              hipStream_t stream) {
    const float* x  = (const float*)d_in[0];   // [8,128,64,64]
    const float* ow = (const float*)d_in[1];   // [54,64,3,3]
    const float* ob = (const float*)d_in[2];   // [54]
    const float* w  = (const float*)d_in[3];   // [128,128,3,3]
    float* out = (float*)d_out;                // [8,128,64,64]

    // ws: x_t bf16 8,388,608 | wt2 294,912 | owf 73,728
    unsigned short* xt  = (unsigned short*)d_ws;
    unsigned short* wt2 = (unsigned short*)((char*)d_ws + 8388608);
    unsigned short* owf = (unsigned short*)((char*)d_ws + 8388608 + 294912);

    hipLaunchKernelGGL(prep, dim3(1232), dim3(256), 0, stream,
                       x, w, ow, xt, wt2, owf);
    hipLaunchKernelGGL(dcn_fused, dim3(1024), dim3(256), 0, stream,
                       xt, owf, ob, wt2, out);
}